// Round 4
// baseline (702.686 us; speedup 1.0000x reference)
//
#include <hip/hip_runtime.h>
#include <math.h>

#define BB 16
#define NN 96
#define NE 256
#define FF (BB*NN)      // 1536
#define ATOM 128
#define EDIM 16
#define HID 128
#define LAT 128
#define RBFN 16
#define CUTOFF 5.0f
#define ZEMB 32
#define E_ATT 1024
#define M0I 64
#define M1I 32
#define M0O 32
#define M1O 16
#define NODE_DIM 160
#define OUT_DIM 80
#define INVD 48
#define WNUM 4608
#define SEG1 2048
#define SEG2 3072
#define SEG3 3584

#define NODE_BLKS (FF/4)   // 384
#define EC_BLKS 16
#define HABS_BLKS 2
#define GATE_BLKS 16
#define STAGE1_BLKS (NODE_BLKS + EC_BLKS + HABS_BLKS + GATE_BLKS)  // 418
#define TPW_BLKS (16*36)   // 576 (1024 rows / 64  x  4608 cols / 128)
#define Q23_BLKS 512
#define BIG_BLKS (TPW_BLKS + Q23_BLKS)  // 1088

__device__ __forceinline__ float silu_f(float x) { return x / (1.0f + expf(-x)); }

// ---------------- init: inv = -1, virr = 0 ----------------
__global__ __launch_bounds__(256) void k_init(int* __restrict__ inv, float* __restrict__ virr) {
    int i = blockIdx.x * 256 + threadIdx.x;
    if (i < FF*OUT_DIM/4) {
        float4 zz = make_float4(0.f, 0.f, 0.f, 0.f);
        ((float4*)virr)[i] = zz;
    }
    if (i < FF) inv[i] = -1;
}

// ---------------- scatter: inv[att_dst[e]] = e ----------------
__global__ __launch_bounds__(256) void k_scatter(const int* __restrict__ att_dst, int* __restrict__ inv) {
    int e = blockIdx.x * 256 + threadIdx.x;
    if (e < E_ATT) inv[att_dst[e]] = e;
}

// ---------------- stage1 mega-kernel ----------------
// [0,384): node pipeline, 4 nodes each (one wave per node)
// [384,400): ec (q layer-1 e_feat part), [400,402): habs1, [402,418): gates
__global__ __launch_bounds__(256) void k_stage1(
    const float* __restrict__ h, const float* __restrict__ z_emb, const int* __restrict__ z,
    const int* __restrict__ absorber, const float* __restrict__ e_feat,
    const int* __restrict__ inv,
    const float* __restrict__ att_dist, const float* __restrict__ att_vec,
    const float* __restrict__ rw1, const float* __restrict__ rb1,
    const float* __restrict__ kw1, const float* __restrict__ kb1,
    const float* __restrict__ kw2, const float* __restrict__ kb2,
    const float* __restrict__ kw3, const float* __restrict__ kb3,
    const float* __restrict__ qw1,
    const float* __restrict__ ew1, const float* __restrict__ eb1,
    const float* __restrict__ ew2, const float* __restrict__ eb2,
    float* __restrict__ y1E, float* __restrict__ envE,
    float* __restrict__ hiddenE, float* __restrict__ kmatw,
    float* __restrict__ ecw, float* __restrict__ habs1w, float* __restrict__ gexp)
{
    __shared__ float smem[3072];
    int blk = blockIdx.x;
    int t = threadIdx.x;

    if (blk < NODE_BLKS) {
        // sin1: [4][184] at 0 (736), l1S: [4][128] at 736, l2S at 1248
        float* sin1 = smem;            // row stride 184; layout: h[0..127], zr[128..159], isabs[160], rbf[161..176]
        float* l1S  = smem + 736;
        float* l2S  = smem + 1248;
        int f0 = blk * 4;
        int r = t >> 6;         // node within block (wave-uniform)
        int c = t & 63;
        int f = f0 + r;
        int b = f / NN, nn = f - b*NN;
        int e = inv[f];
        bool att_ = ((unsigned)e < E_ATT);
        float d = att_ ? att_dist[e] : 0.0f;
        {   // h stage: float2 per lane
            float2 hv = *(const float2*)&h[f*ATOM + 2*c];
            sin1[r*184 + 2*c] = hv.x; sin1[r*184 + 2*c + 1] = hv.y;
        }
        if (c < ZEMB) sin1[r*184 + ATOM + c] = z_emb[z[f]*ZEMB + c];
        if (c >= 32 && c < 48) {
            int j = c - 32;
            const float delta = CUTOFF / (RBFN - 1);
            float diff = d - j*delta;
            sin1[r*184 + ATOM + ZEMB + 1 + j] = expf(-diff*diff / (2.0f*delta*delta));
        }
        if (c == 48) sin1[r*184 + ATOM + ZEMB] = (absorber[b] == nn) ? 1.0f : 0.0f;
        if (c == 49 && att_) {
            envE[e] = (d < CUTOFF) ? 0.5f*(cosf(3.14159265358979323846f*d/CUTOFF) + 1.0f) : 0.0f;
            float vx = att_vec[3*e], vy = att_vec[3*e+1], vz = att_vec[3*e+2];
            float nrm = sqrtf(vx*vx + vy*vy + vz*vz);
            float is = 1.0f / fmaxf(nrm, 1e-8f);
            const float s3 = 1.7320508075688772f;
            y1E[3*e]   = s3*vx*is;
            y1E[3*e+1] = s3*vy*is;
            y1E[3*e+2] = s3*vz*is;
        }
        __syncthreads();
        int c2 = 2*c;
        if (att_) {   // hidden = silu(w_in @ rw1 + rb1): 49 -> 128 (wave-uniform branch)
            float2 acc = *(const float2*)&rb1[c2];
            for (int i = 0; i < ZEMB + 1 + RBFN; i++) {
                float a = sin1[r*184 + ATOM + i];
                float2 w = *(const float2*)&rw1[i*HID + c2];
                acc.x += a*w.x; acc.y += a*w.y;
            }
            float2 o; o.x = silu_f(acc.x); o.y = silu_f(acc.y);
            *(float2*)&hiddenE[e*HID + c2] = o;
        }
        {   // k layer 1: 177 -> 128
            float2 acc = *(const float2*)&kb1[c2];
            for (int i = 0; i < ATOM + ZEMB + 1 + RBFN; i++) {
                float a = sin1[r*184 + i];
                float2 w = *(const float2*)&kw1[i*HID + c2];
                acc.x += a*w.x; acc.y += a*w.y;
            }
            l1S[r*128 + c2] = silu_f(acc.x); l1S[r*128 + c2 + 1] = silu_f(acc.y);
        }
        __syncthreads();
        {   // k layer 2
            float2 acc = *(const float2*)&kb2[c2];
            for (int i = 0; i < HID; i++) {
                float a = l1S[r*128 + i];
                float2 w = *(const float2*)&kw2[i*HID + c2];
                acc.x += a*w.x; acc.y += a*w.y;
            }
            l2S[r*128 + c2] = silu_f(acc.x); l2S[r*128 + c2 + 1] = silu_f(acc.y);
        }
        __syncthreads();
        {   // k layer 3
            float2 acc = *(const float2*)&kb3[c2];
            for (int i = 0; i < HID; i++) {
                float a = l2S[r*128 + i];
                float2 w = *(const float2*)&kw3[i*HID + c2];
                acc.x += a*w.x; acc.y += a*w.y;
            }
            *(float2*)&kmatw[f*HID + c2] = acc;
        }
    } else if (blk < NODE_BLKS + EC_BLKS) {
        float* ef = smem;   // 16 x 16
        int e0 = (blk - NODE_BLKS) * 16;
        { int e = t >> 4, i = t & 15; ef[e*16 + i] = e_feat[(e0 + e)*EDIM + i]; }
        __syncthreads();
        int r = t >> 4, c0 = (t & 15)*8;
        float4 a0 = make_float4(0,0,0,0), a1 = a0;
        for (int i = 0; i < EDIM; i++) {
            float a = ef[r*16 + i];
            float4 w0 = *(const float4*)&qw1[(ATOM + i)*HID + c0];
            float4 w1 = *(const float4*)&qw1[(ATOM + i)*HID + c0 + 4];
            a0.x += a*w0.x; a0.y += a*w0.y; a0.z += a*w0.z; a0.w += a*w0.w;
            a1.x += a*w1.x; a1.y += a*w1.y; a1.z += a*w1.z; a1.w += a*w1.w;
        }
        *(float4*)&ecw[(e0 + r)*HID + c0] = a0;
        *(float4*)&ecw[(e0 + r)*HID + c0 + 4] = a1;
    } else if (blk < NODE_BLKS + EC_BLKS + HABS_BLKS) {
        float* hr = smem;   // 8 x 128
        int b0 = (blk - NODE_BLKS - EC_BLKS) * 8;
        {
            int r = t >> 5, i4 = t & 31;
            int b = b0 + r;
            int a = absorber[b];
            *(float4*)&hr[r*128 + i4*4] = *(const float4*)&h[(b*NN + a)*ATOM + i4*4];
        }
        __syncthreads();
        int r = t >> 5, c0 = (t & 31)*4;
        float4 acc = make_float4(0,0,0,0);
        for (int i = 0; i < ATOM; i++) {
            float a = hr[r*128 + i];
            float4 w = *(const float4*)&qw1[i*HID + c0];
            acc.x += a*w.x; acc.y += a*w.y; acc.z += a*w.z; acc.w += a*w.w;
        }
        *(float4*)&habs1w[(b0 + r)*HID + c0] = acc;
    } else {
        float* ef  = smem;            // 16x16
        float* l1g = smem + 256;      // 16x128
        float* gg  = smem + 256 + 2048; // 16x48
        int e0 = (blk - NODE_BLKS - EC_BLKS - HABS_BLKS) * 16;
        { int e = t >> 4, i = t & 15; ef[e*16 + i] = e_feat[(e0 + e)*EDIM + i]; }
        __syncthreads();
        int r = t >> 4, c0 = (t & 15)*8;
        {
            float4 a0 = *(const float4*)&eb1[c0];
            float4 a1 = *(const float4*)&eb1[c0 + 4];
            for (int i = 0; i < EDIM; i++) {
                float a = ef[r*16 + i];
                float4 w0 = *(const float4*)&ew1[i*HID + c0];
                float4 w1 = *(const float4*)&ew1[i*HID + c0 + 4];
                a0.x += a*w0.x; a0.y += a*w0.y; a0.z += a*w0.z; a0.w += a*w0.w;
                a1.x += a*w1.x; a1.y += a*w1.y; a1.z += a*w1.z; a1.w += a*w1.w;
            }
            l1g[r*128 + c0]   = silu_f(a0.x); l1g[r*128 + c0+1] = silu_f(a0.y);
            l1g[r*128 + c0+2] = silu_f(a0.z); l1g[r*128 + c0+3] = silu_f(a0.w);
            l1g[r*128 + c0+4] = silu_f(a1.x); l1g[r*128 + c0+5] = silu_f(a1.y);
            l1g[r*128 + c0+6] = silu_f(a1.z); l1g[r*128 + c0+7] = silu_f(a1.w);
        }
        __syncthreads();
        for (int u = t; u < 16*48; u += 256) {
            int e = u / 48, j = u - 48*(u/48);
            float acc = eb2[j];
            for (int i = 0; i < HID; i++) acc += l1g[e*128 + i]*ew2[i*48 + j];
            gg[e*48 + j] = acc;
        }
        __syncthreads();
        for (int u = t; u < 16*80; u += 256) {
            int e = u / 80, cc = u - 80*(u/80);
            gexp[(e0 + e)*OUT_DIM + cc] = (cc < M0O) ? gg[e*48 + cc] : gg[e*48 + M0O + (cc - M0O)/3];
        }
    }
}

// ---------------- fused big launch: tpw GEMM (1024x4608) + q layers 2-3 ----------------
__global__ __launch_bounds__(256) void k_big(
    const float* __restrict__ hiddenE, const float* __restrict__ rw2, const float* __restrict__ rb2,
    const float* __restrict__ habs1, const float* __restrict__ ec, const float* __restrict__ qb1,
    const float* __restrict__ qw2, const float* __restrict__ qb2,
    const float* __restrict__ qw3, const float* __restrict__ qb3,
    float* __restrict__ tpwE, float* __restrict__ qmat)
{
    __shared__ float smem[6208];
    int blk = blockIdx.x;
    int t = threadIdx.x;
    if (blk < TPW_BLKS) {
        // As: 64x33 at 0 (2112), Bs: 32x128 at 2112
        float* As = smem;
        float* Bs = smem + 2112;
        int col0 = (blk % 36) * 128;
        int row0 = (blk / 36) * 64;
        float4 acc[8];
        for (int j = 0; j < 8; j++) acc[j] = make_float4(0,0,0,0);
        int tc = t & 31, tr = t >> 5;
        for (int k0 = 0; k0 < HID; k0 += 32) {
            for (int p = 0; p < 2; p++) {
                int idx = t + 256*p;
                int rr = idx >> 3, k4 = idx & 7;
                float4 hv = *(const float4*)&hiddenE[(row0 + rr)*HID + k0 + k4*4];
                As[rr*33 + k4*4]   = hv.x; As[rr*33 + k4*4+1] = hv.y;
                As[rr*33 + k4*4+2] = hv.z; As[rr*33 + k4*4+3] = hv.w;
            }
            for (int p = 0; p < 4; p++) {
                int idx = t + 256*p;
                int kk = idx >> 5, c4 = idx & 31;
                *(float4*)&Bs[kk*128 + c4*4] = *(const float4*)&rw2[(k0 + kk)*WNUM + col0 + c4*4];
            }
            __syncthreads();
            for (int kk = 0; kk < 32; kk++) {
                float4 bv = *(float4*)&Bs[kk*128 + tc*4];
                for (int j = 0; j < 8; j++) {
                    float a = As[(tr*8 + j)*33 + kk];
                    acc[j].x += a*bv.x; acc[j].y += a*bv.y; acc[j].z += a*bv.z; acc[j].w += a*bv.w;
                }
            }
            __syncthreads();
        }
        float4 bias = *(const float4*)&rb2[col0 + tc*4];
        for (int j = 0; j < 8; j++) {
            int r = row0 + tr*8 + j;
            float4 o;
            o.x = acc[j].x + bias.x; o.y = acc[j].y + bias.y;
            o.z = acc[j].z + bias.z; o.w = acc[j].w + bias.w;
            *(float4*)&tpwE[(long)r*WNUM + col0 + tc*4] = o;
        }
    } else {
        // q layers 2-3, 8 rows per block
        float* l1S = smem;          // 8x128
        float* l2S = smem + 1024;   // 8x128
        int r0 = (blk - TPW_BLKS) * 8;
        for (int p = 0; p < 4; p++) {
            int idx = t + 256*p;    // 0..1023
            int rr = idx >> 7, i = idx & 127;
            int be = r0 + rr; int b = be >> 8; int e = be & 255;
            l1S[rr*128 + i] = silu_f(habs1[b*HID + i] + ec[e*HID + i] + qb1[i]);
        }
        __syncthreads();
        int r = t >> 5, c0 = (t & 31)*4;
        {
            float4 a0 = *(const float4*)&qb2[c0];
            for (int i = 0; i < HID; i++) {
                float a = l1S[r*128 + i];
                float4 w = *(const float4*)&qw2[i*HID + c0];
                a0.x += a*w.x; a0.y += a*w.y; a0.z += a*w.z; a0.w += a*w.w;
            }
            l2S[r*128 + c0]   = silu_f(a0.x); l2S[r*128 + c0+1] = silu_f(a0.y);
            l2S[r*128 + c0+2] = silu_f(a0.z); l2S[r*128 + c0+3] = silu_f(a0.w);
        }
        __syncthreads();
        {
            float4 a0 = *(const float4*)&qb3[c0];
            for (int i = 0; i < HID; i++) {
                float a = l2S[r*128 + i];
                float4 w = *(const float4*)&qw3[i*HID + c0];
                a0.x += a*w.x; a0.y += a*w.y; a0.z += a*w.z; a0.w += a*w.w;
            }
            *(float4*)&qmat[(r0 + r)*LAT + c0] = a0;
        }
    }
}

// ---------------- tensor product per edge -> virr (node layout) ----------------
__global__ __launch_bounds__(128) void k_tp(
    const float* __restrict__ h_full, const float* __restrict__ tpwE,
    const int* __restrict__ att_dst,
    const float* __restrict__ envE, const float* __restrict__ y1E,
    float* __restrict__ virr)
{
    int e = blockIdx.x; int t = threadIdx.x;
    int f = att_dst[e];
    __shared__ float x0[M0I];
    __shared__ float x1f[M1I*3];
    __shared__ float xy[M1I];
    __shared__ float y1s[3];
    const float* hf = h_full + f*NODE_DIM;
    if (t < M0I) x0[t] = hf[t];
    if (t < M1I*3) x1f[t] = hf[M0I + t];
    if (t < 3) y1s[t] = y1E[3*e + t];
    __syncthreads();
    if (t < M1I) xy[t] = x1f[3*t]*y1s[0] + x1f[3*t+1]*y1s[1] + x1f[3*t+2]*y1s[2];
    __syncthreads();
    float scale = envE[e];
    const float* w = tpwE + (long)e*WNUM;
    const float alpha = 0.10206207261596575f;  // 1/sqrt(96)
    const float cc = 0.5773502691896258f;      // 1/sqrt(3)
    if (t < M0O) {
        float t00 = 0.f, t11 = 0.f;
        for (int i = 0; i < M0I; i++) t00 += x0[i]*w[i*M0O + t];
        for (int i = 0; i < M1I; i++) t11 += xy[i]*w[SEG3 + i*M0O + t];
        virr[f*OUT_DIM + t] = alpha*(t00 + cc*t11)*scale;
    } else if (t < M0O + 3*M1O) {
        int idx = t - M0O; int o = idx/3, m = idx - 3*o;
        float t01 = 0.f, t10 = 0.f;
        for (int i = 0; i < M0I; i++) t01 += x0[i]*w[SEG1 + i*M1O + o];
        for (int i = 0; i < M1I; i++) t10 += x1f[i*3 + m]*w[SEG2 + i*M1O + o];
        virr[f*OUT_DIM + t] = alpha*cc*(t01*y1s[m] + t10)*scale;
    }
}

// ---------------- attention: (b, 8e) blocks; K from L2; V/gates in LDS ----------------
__global__ __launch_bounds__(256) void k_att(
    const float* __restrict__ qmat, const float* __restrict__ kmat, const int* __restrict__ inv,
    const float* __restrict__ virr, const float* __restrict__ gexp,
    float* __restrict__ invm)
{
    int b  = blockIdx.x >> 5;
    int e0 = (blockIdx.x & 31) * 8;
    int t = threadIdx.x;
    __shared__ float qS[8][132];
    __shared__ float vS[NN][84];
    __shared__ float aS[8][100];
    __shared__ float gS[8][84];
    __shared__ float ocS[8][84];
    __shared__ float mS[NN];

    for (int p = 0; p < 4; p++) {
        int idx = t + 256*p; int el = idx >> 7, i = idx & 127;
        qS[el][i] = qmat[(b*NE + e0 + el)*LAT + i];
    }
    for (int idx = t; idx < NN*OUT_DIM; idx += 256) {
        int n = idx / OUT_DIM, cc = idx - n*OUT_DIM;
        vS[n][cc] = virr[(b*NN + n)*OUT_DIM + cc];
    }
    for (int idx = t; idx < 8*OUT_DIM; idx += 256) {
        int el = idx / OUT_DIM, cc = idx - el*OUT_DIM;
        gS[el][cc] = gexp[(e0 + el)*OUT_DIM + cc];
    }
    if (t < NN) mS[t] = ((unsigned)inv[b*NN + t] < E_ATT) ? 1.0f : 0.0f;
    __syncthreads();

    {
        int el = t >> 5;
        int ng = t & 31;
        float a0 = 0.f, a1 = 0.f, a2 = 0.f;
        const float* k0p = kmat + (b*NN + ng)*LAT;
        const float* k1p = kmat + (b*NN + ng + 32)*LAT;
        const float* k2p = kmat + (b*NN + ng + 64)*LAT;
        for (int i = 0; i < LAT; i += 4) {
            float4 qv = *(float4*)&qS[el][i];
            float4 k0 = *(const float4*)&k0p[i];
            float4 k1 = *(const float4*)&k1p[i];
            float4 k2 = *(const float4*)&k2p[i];
            a0 += qv.x*k0.x + qv.y*k0.y + qv.z*k0.z + qv.w*k0.w;
            a1 += qv.x*k1.x + qv.y*k1.y + qv.z*k1.z + qv.w*k1.w;
            a2 += qv.x*k2.x + qv.y*k2.y + qv.z*k2.z + qv.w*k2.w;
        }
        const float scale = 0.04419417382415922f;  // (1/HEADS)*HD^-0.5
        aS[el][ng]      = (mS[ng]      != 0.f) ? a0*scale : -1e9f;
        aS[el][ng + 32] = (mS[ng + 32] != 0.f) ? a1*scale : -1e9f;
        aS[el][ng + 64] = (mS[ng + 64] != 0.f) ? a2*scale : -1e9f;
    }
    __syncthreads();

    if (t < 8) {
        float mx = -INFINITY;
        for (int n = 0; n < NN; n++) mx = fmaxf(mx, aS[t][n]);
        float sm = 0.f;
        for (int n = 0; n < NN; n++) { float ex = expf(aS[t][n] - mx); aS[t][n] = ex; sm += ex; }
        float s2 = 0.f;
        for (int n = 0; n < NN; n++) {
            float a = (mS[n] != 0.f) ? aS[t][n]/sm : 0.f;
            aS[t][n] = a; s2 += a;
        }
        float is = 1.0f / fmaxf(s2, 1e-8f);
        for (int n = 0; n < NN; n++) aS[t][n] *= is;
    }
    __syncthreads();

    for (int u = t; u < 8*OUT_DIM; u += 256) {
        int el = u / OUT_DIM, cc = u - el*OUT_DIM;
        float acc = 0.f;
        for (int n = 0; n < NN; n++) acc += aS[el][n]*vS[n][cc];
        ocS[el][cc] = acc * gS[el][cc];
    }
    __syncthreads();

    for (int u = t; u < 8*INVD; u += 256) {
        int el = u / INVD, j = u - el*INVD;
        float val;
        if (j < M0O) val = ocS[el][j];
        else {
            int o = j - M0O;
            float x = ocS[el][M0O + 3*o], y = ocS[el][M0O + 3*o + 1], zz = ocS[el][M0O + 3*o + 2];
            val = sqrtf(x*x + y*y + zz*zz + 1e-12f);
        }
        invm[(b*NE + e0 + el)*INVD + j] = val;
    }
}

// ---------------- final MLP: 4096 rows x (48->128->128->128), 8 rows/block ----------------
__global__ __launch_bounds__(256) void k_final(
    const float* __restrict__ invm,
    const float* __restrict__ ow1, const float* __restrict__ ob1,
    const float* __restrict__ ow2, const float* __restrict__ ob2,
    const float* __restrict__ ow3, const float* __restrict__ ob3,
    float* __restrict__ out)
{
    int r0 = blockIdx.x * 8;
    int t = threadIdx.x;
    int r = t >> 5, c0 = (t & 31)*4;
    __shared__ float inS[8][INVD];
    __shared__ float l1S[8][HID];
    __shared__ float l2S[8][HID];
    for (int idx = t; idx < 8*INVD; idx += 256) {
        int rr = idx / INVD, j = idx - rr*INVD;
        inS[rr][j] = invm[(r0 + rr)*INVD + j];
    }
    __syncthreads();
    {
        float4 a0 = *(const float4*)&ob1[c0];
        for (int i = 0; i < INVD; i++) {
            float a = inS[r][i];
            float4 w = *(const float4*)&ow1[i*HID + c0];
            a0.x += a*w.x; a0.y += a*w.y; a0.z += a*w.z; a0.w += a*w.w;
        }
        l1S[r][c0]   = silu_f(a0.x); l1S[r][c0+1] = silu_f(a0.y);
        l1S[r][c0+2] = silu_f(a0.z); l1S[r][c0+3] = silu_f(a0.w);
    }
    __syncthreads();
    {
        float4 a0 = *(const float4*)&ob2[c0];
        for (int i = 0; i < HID; i++) {
            float a = l1S[r][i];
            float4 w = *(const float4*)&ow2[i*HID + c0];
            a0.x += a*w.x; a0.y += a*w.y; a0.z += a*w.z; a0.w += a*w.w;
        }
        l2S[r][c0]   = silu_f(a0.x); l2S[r][c0+1] = silu_f(a0.y);
        l2S[r][c0+2] = silu_f(a0.z); l2S[r][c0+3] = silu_f(a0.w);
    }
    __syncthreads();
    {
        float4 a0 = *(const float4*)&ob3[c0];
        for (int i = 0; i < HID; i++) {
            float a = l2S[r][i];
            float4 w = *(const float4*)&ow3[i*HID + c0];
            a0.x += a*w.x; a0.y += a*w.y; a0.z += a*w.z; a0.w += a*w.w;
        }
        *(float4*)&out[(r0 + r)*LAT + c0] = a0;
    }
}

extern "C" void kernel_launch(void* const* d_in, const int* in_sizes, int n_in,
                              void* d_out, int out_size, void* d_ws, size_t ws_size,
                              hipStream_t stream) {
    const float* h        = (const float*)d_in[0];
    const float* h_full   = (const float*)d_in[1];
    const float* e_feat   = (const float*)d_in[2];
    const float* att_dist = (const float*)d_in[3];
    const float* att_vec  = (const float*)d_in[4];
    const float* z_emb    = (const float*)d_in[5];
    const float* rw1 = (const float*)d_in[6];  const float* rb1 = (const float*)d_in[7];
    const float* rw2 = (const float*)d_in[8];  const float* rb2 = (const float*)d_in[9];
    const float* ew1 = (const float*)d_in[10]; const float* eb1 = (const float*)d_in[11];
    const float* ew2 = (const float*)d_in[12]; const float* eb2 = (const float*)d_in[13];
    const float* qw1 = (const float*)d_in[14]; const float* qb1 = (const float*)d_in[15];
    const float* qw2 = (const float*)d_in[16]; const float* qb2 = (const float*)d_in[17];
    const float* qw3 = (const float*)d_in[18]; const float* qb3 = (const float*)d_in[19];
    const float* kw1 = (const float*)d_in[20]; const float* kb1 = (const float*)d_in[21];
    const float* kw2 = (const float*)d_in[22]; const float* kb2 = (const float*)d_in[23];
    const float* kw3 = (const float*)d_in[24]; const float* kb3 = (const float*)d_in[25];
    const float* ow1 = (const float*)d_in[26]; const float* ob1 = (const float*)d_in[27];
    const float* ow2 = (const float*)d_in[28]; const float* ob2 = (const float*)d_in[29];
    const float* ow3 = (const float*)d_in[30]; const float* ob3 = (const float*)d_in[31];
    const int* z        = (const int*)d_in[32];
    const int* absorber = (const int*)d_in[34];
    const int* att_dst  = (const int*)d_in[35];

    float* ws = (float*)d_ws;
    int*   inv     = (int*)ws;                    // 1536
    float* y1E     = ws + 1536;                   // 3072
    float* envE    = ws + 4608;                   // 1024
    float* hiddenE = ws + 5632;                   // 131072
    float* kmat    = ws + 136704;                 // 196608
    float* qmat    = ws + 333312;                 // 524288
    float* gexp    = ws + 857600;                 // 20480
    float* virr    = ws + 878080;                 // 122880
    float* habs1   = ws + 1000960;                // 2048
    float* ec      = ws + 1003008;                // 32768
    float* tpwE    = ws + 1035776;                // 1024*4608 = 4718592
    float* invm    = tpwE;                        // alias: tpwE dead after k_tp

    float* out = (float*)d_out;

    k_init<<<120, 256, 0, stream>>>(inv, virr);
    k_scatter<<<4, 256, 0, stream>>>(att_dst, inv);
    k_stage1<<<STAGE1_BLKS, 256, 0, stream>>>(h, z_emb, z, absorber, e_feat, inv,
                                              att_dist, att_vec,
                                              rw1, rb1, kw1, kb1, kw2, kb2, kw3, kb3,
                                              qw1, ew1, eb1, ew2, eb2,
                                              y1E, envE, hiddenE, kmat,
                                              ec, habs1, gexp);
    k_big<<<BIG_BLKS, 256, 0, stream>>>(hiddenE, rw2, rb2, habs1, ec, qb1,
                                        qw2, qb2, qw3, qb3, tpwE, qmat);
    k_tp<<<E_ATT, 128, 0, stream>>>(h_full, tpwE, att_dst, envE, y1E, virr);
    k_att<<<BB*32, 256, 0, stream>>>(qmat, kmat, inv, virr, gexp, invm);
    k_final<<<BB*NE/8, 256, 0, stream>>>(invm, ow1, ob1, ow2, ob2, ow3, ob3, out);
}

// Round 5
// 294.429 us; speedup vs baseline: 2.3866x; 2.3866x over previous
//
#include <hip/hip_runtime.h>
#include <hip/hip_fp16.h>
#include <math.h>

#define BB 16
#define NN 96
#define NE 256
#define FF (BB*NN)      // 1536
#define ATOM 128
#define EDIM 16
#define HID 128
#define LAT 128
#define RBFN 16
#define CUTOFF 5.0f
#define ZEMB 32
#define E_ATT 1024
#define M0I 64
#define M1I 32
#define M0O 32
#define M1O 16
#define NODE_DIM 160
#define OUT_DIM 80
#define INVD 48
#define WNUM 4608
#define SEG1 2048
#define SEG2 3072
#define SEG3 3584

#define NODE_BLKS (FF/8)   // 192
#define EC_BLKS 16
#define HABS_BLKS 2
#define GATE_BLKS 16
#define STAGE1_BLKS (NODE_BLKS + EC_BLKS + HABS_BLKS + GATE_BLKS)  // 226

__device__ __forceinline__ float silu_f(float x) { return x / (1.0f + expf(-x)); }

// ---------------- prep: inv init + scatter + per-edge y1/env (one block) ----------------
__global__ __launch_bounds__(1024) void k_prep(
    const int* __restrict__ att_dst, const float* __restrict__ att_dist,
    const float* __restrict__ att_vec,
    int* __restrict__ inv, float* __restrict__ y1E, float* __restrict__ envE)
{
    int t = threadIdx.x;
    inv[t] = -1;
    if (t < FF - 1024) inv[1024 + t] = -1;
    {
        float d = att_dist[t];
        envE[t] = (d < CUTOFF) ? 0.5f*(cosf(3.14159265358979323846f*d/CUTOFF) + 1.0f) : 0.0f;
        float vx = att_vec[3*t], vy = att_vec[3*t+1], vz = att_vec[3*t+2];
        float nrm = sqrtf(vx*vx + vy*vy + vz*vz);
        float is = 1.0f / fmaxf(nrm, 1e-8f);
        const float s3 = 1.7320508075688772f;
        y1E[3*t]   = s3*vx*is;
        y1E[3*t+1] = s3*vy*is;
        y1E[3*t+2] = s3*vz*is;
    }
    __syncthreads();
    inv[att_dst[t]] = t;
}

// ---------------- stage1 mega-kernel ----------------
// [0,192): node pipeline (8 nodes: features + hidden + k-MLP)
// [192,208): ec, [208,210): habs1, [210,226): gates
__global__ __launch_bounds__(256) void k_stage1(
    const float* __restrict__ h, const float* __restrict__ z_emb, const int* __restrict__ z,
    const int* __restrict__ absorber, const float* __restrict__ e_feat,
    const int* __restrict__ inv, const float* __restrict__ att_dist,
    const float* __restrict__ rw1, const float* __restrict__ rb1,
    const float* __restrict__ kw1, const float* __restrict__ kb1,
    const float* __restrict__ kw2, const float* __restrict__ kb2,
    const float* __restrict__ kw3, const float* __restrict__ kb3,
    const float* __restrict__ qw1,
    const float* __restrict__ ew1, const float* __restrict__ eb1,
    const float* __restrict__ ew2, const float* __restrict__ eb2,
    float* __restrict__ hiddenE, float* __restrict__ kmatw,
    float* __restrict__ ecw, float* __restrict__ habs1w, float* __restrict__ gexp)
{
    __shared__ float smem[3488];
    int blk = blockIdx.x;
    int t = threadIdx.x;

    if (blk < NODE_BLKS) {
        float (*sin1)[180] = (float(*)[180])smem;            // 8 x 180 (177 used)
        float (*l1S)[128]  = (float(*)[128])(smem + 1440);
        float (*l2S)[128]  = (float(*)[128])(smem + 1440 + 1024);
        int f0 = blk * 8;
        {   // h: 8 x 128 = 256 float4
            int n = t >> 5, i4 = t & 31;
            *(float4*)&sin1[n][i4*4] = *(const float4*)&h[(f0 + n)*ATOM + i4*4];
        }
        {   // zr: 8 x 32
            int n = t >> 5, j = t & 31;
            sin1[n][ATOM + j] = z_emb[z[f0 + n]*ZEMB + j];
        }
        if (t < 128) {  // rbf: 8 x 16
            int n = t >> 4, j = t & 15;
            int e = inv[f0 + n];
            float d = ((unsigned)e < E_ATT) ? att_dist[e] : 0.0f;
            const float delta = CUTOFF / (RBFN - 1);
            float diff = d - j*delta;
            sin1[n][ATOM + ZEMB + 1 + j] = expf(-diff*diff / (2.0f*delta*delta));
        }
        if (t < 8) {    // is_abs
            int f = f0 + t;
            int b = f / NN, nn = f - b*NN;
            sin1[t][ATOM + ZEMB] = (absorber[b] == nn) ? 1.0f : 0.0f;
        }
        __syncthreads();
        int r = t >> 5, c0 = (t & 31)*4;
        int e = inv[f0 + r];
        bool att_ = ((unsigned)e < E_ATT);
        if (att_) {   // hidden = silu(w_in @ rw1 + rb1): 49 -> 128
            float4 a0 = *(const float4*)&rb1[c0];
            float4 a1 = make_float4(0,0,0,0);
            #pragma unroll 8
            for (int i = 0; i < 48; i += 2) {
                float x0v = sin1[r][ATOM + i], x1v = sin1[r][ATOM + i + 1];
                float4 w0 = *(const float4*)&rw1[i*HID + c0];
                float4 w1 = *(const float4*)&rw1[(i+1)*HID + c0];
                a0.x += x0v*w0.x; a0.y += x0v*w0.y; a0.z += x0v*w0.z; a0.w += x0v*w0.w;
                a1.x += x1v*w1.x; a1.y += x1v*w1.y; a1.z += x1v*w1.z; a1.w += x1v*w1.w;
            }
            {
                float x0v = sin1[r][ATOM + 48];
                float4 w0 = *(const float4*)&rw1[48*HID + c0];
                a0.x += x0v*w0.x; a0.y += x0v*w0.y; a0.z += x0v*w0.z; a0.w += x0v*w0.w;
            }
            float4 o;
            o.x = silu_f(a0.x + a1.x); o.y = silu_f(a0.y + a1.y);
            o.z = silu_f(a0.z + a1.z); o.w = silu_f(a0.w + a1.w);
            *(float4*)&hiddenE[e*HID + c0] = o;
        }
        {   // k layer 1: 177 -> 128
            float4 a0 = *(const float4*)&kb1[c0];
            float4 a1 = make_float4(0,0,0,0);
            #pragma unroll 8
            for (int i = 0; i < 176; i += 2) {
                float x0v = sin1[r][i], x1v = sin1[r][i + 1];
                float4 w0 = *(const float4*)&kw1[i*HID + c0];
                float4 w1 = *(const float4*)&kw1[(i+1)*HID + c0];
                a0.x += x0v*w0.x; a0.y += x0v*w0.y; a0.z += x0v*w0.z; a0.w += x0v*w0.w;
                a1.x += x1v*w1.x; a1.y += x1v*w1.y; a1.z += x1v*w1.z; a1.w += x1v*w1.w;
            }
            {
                float x0v = sin1[r][176];
                float4 w0 = *(const float4*)&kw1[176*HID + c0];
                a0.x += x0v*w0.x; a0.y += x0v*w0.y; a0.z += x0v*w0.z; a0.w += x0v*w0.w;
            }
            l1S[r][c0]   = silu_f(a0.x + a1.x); l1S[r][c0+1] = silu_f(a0.y + a1.y);
            l1S[r][c0+2] = silu_f(a0.z + a1.z); l1S[r][c0+3] = silu_f(a0.w + a1.w);
        }
        __syncthreads();
        {   // k layer 2
            float4 a0 = *(const float4*)&kb2[c0];
            float4 a1 = make_float4(0,0,0,0);
            #pragma unroll 8
            for (int i = 0; i < HID; i += 2) {
                float x0v = l1S[r][i], x1v = l1S[r][i + 1];
                float4 w0 = *(const float4*)&kw2[i*HID + c0];
                float4 w1 = *(const float4*)&kw2[(i+1)*HID + c0];
                a0.x += x0v*w0.x; a0.y += x0v*w0.y; a0.z += x0v*w0.z; a0.w += x0v*w0.w;
                a1.x += x1v*w1.x; a1.y += x1v*w1.y; a1.z += x1v*w1.z; a1.w += x1v*w1.w;
            }
            l2S[r][c0]   = silu_f(a0.x + a1.x); l2S[r][c0+1] = silu_f(a0.y + a1.y);
            l2S[r][c0+2] = silu_f(a0.z + a1.z); l2S[r][c0+3] = silu_f(a0.w + a1.w);
        }
        __syncthreads();
        {   // k layer 3
            float4 a0 = *(const float4*)&kb3[c0];
            float4 a1 = make_float4(0,0,0,0);
            #pragma unroll 8
            for (int i = 0; i < HID; i += 2) {
                float x0v = l2S[r][i], x1v = l2S[r][i + 1];
                float4 w0 = *(const float4*)&kw3[i*HID + c0];
                float4 w1 = *(const float4*)&kw3[(i+1)*HID + c0];
                a0.x += x0v*w0.x; a0.y += x0v*w0.y; a0.z += x0v*w0.z; a0.w += x0v*w0.w;
                a1.x += x1v*w1.x; a1.y += x1v*w1.y; a1.z += x1v*w1.z; a1.w += x1v*w1.w;
            }
            float4 o;
            o.x = a0.x + a1.x; o.y = a0.y + a1.y; o.z = a0.z + a1.z; o.w = a0.w + a1.w;
            *(float4*)&kmatw[(f0 + r)*HID + c0] = o;
        }
    } else if (blk < NODE_BLKS + EC_BLKS) {
        float (*ef)[16] = (float(*)[16])smem;
        int e0 = (blk - NODE_BLKS) * 16;
        { int e = t >> 4, i = t & 15; ef[e][i] = e_feat[(e0 + e)*EDIM + i]; }
        __syncthreads();
        int r = t >> 4, c0 = (t & 15)*8;
        float4 a0 = make_float4(0,0,0,0), a1 = a0;
        #pragma unroll
        for (int i = 0; i < EDIM; i++) {
            float a = ef[r][i];
            float4 w0 = *(const float4*)&qw1[(ATOM + i)*HID + c0];
            float4 w1 = *(const float4*)&qw1[(ATOM + i)*HID + c0 + 4];
            a0.x += a*w0.x; a0.y += a*w0.y; a0.z += a*w0.z; a0.w += a*w0.w;
            a1.x += a*w1.x; a1.y += a*w1.y; a1.z += a*w1.z; a1.w += a*w1.w;
        }
        *(float4*)&ecw[(e0 + r)*HID + c0] = a0;
        *(float4*)&ecw[(e0 + r)*HID + c0 + 4] = a1;
    } else if (blk < NODE_BLKS + EC_BLKS + HABS_BLKS) {
        float (*hr)[128] = (float(*)[128])smem;
        int b0 = (blk - NODE_BLKS - EC_BLKS) * 8;
        {
            int r = t >> 5, i4 = t & 31;
            int b = b0 + r;
            int a = absorber[b];
            *(float4*)&hr[r][i4*4] = *(const float4*)&h[(b*NN + a)*ATOM + i4*4];
        }
        __syncthreads();
        int r = t >> 5, c0 = (t & 31)*4;
        float4 a0 = make_float4(0,0,0,0), a1 = a0;
        #pragma unroll 8
        for (int i = 0; i < ATOM; i += 2) {
            float x0v = hr[r][i], x1v = hr[r][i+1];
            float4 w0 = *(const float4*)&qw1[i*HID + c0];
            float4 w1 = *(const float4*)&qw1[(i+1)*HID + c0];
            a0.x += x0v*w0.x; a0.y += x0v*w0.y; a0.z += x0v*w0.z; a0.w += x0v*w0.w;
            a1.x += x1v*w1.x; a1.y += x1v*w1.y; a1.z += x1v*w1.z; a1.w += x1v*w1.w;
        }
        float4 o;
        o.x = a0.x + a1.x; o.y = a0.y + a1.y; o.z = a0.z + a1.z; o.w = a0.w + a1.w;
        *(float4*)&habs1w[(b0 + r)*HID + c0] = o;
    } else {
        float (*ef)[16]   = (float(*)[16])smem;
        float (*l1g)[128] = (float(*)[128])(smem + 256);
        float (*gg)[48]   = (float(*)[48])(smem + 256 + 2048);
        int e0 = (blk - NODE_BLKS - EC_BLKS - HABS_BLKS) * 16;
        { int e = t >> 4, i = t & 15; ef[e][i] = e_feat[(e0 + e)*EDIM + i]; }
        __syncthreads();
        int r = t >> 4, c0 = (t & 15)*8;
        {
            float4 a0 = *(const float4*)&eb1[c0];
            float4 a1 = *(const float4*)&eb1[c0 + 4];
            #pragma unroll
            for (int i = 0; i < EDIM; i++) {
                float a = ef[r][i];
                float4 w0 = *(const float4*)&ew1[i*HID + c0];
                float4 w1 = *(const float4*)&ew1[i*HID + c0 + 4];
                a0.x += a*w0.x; a0.y += a*w0.y; a0.z += a*w0.z; a0.w += a*w0.w;
                a1.x += a*w1.x; a1.y += a*w1.y; a1.z += a*w1.z; a1.w += a*w1.w;
            }
            l1g[r][c0]   = silu_f(a0.x); l1g[r][c0+1] = silu_f(a0.y);
            l1g[r][c0+2] = silu_f(a0.z); l1g[r][c0+3] = silu_f(a0.w);
            l1g[r][c0+4] = silu_f(a1.x); l1g[r][c0+5] = silu_f(a1.y);
            l1g[r][c0+6] = silu_f(a1.z); l1g[r][c0+7] = silu_f(a1.w);
        }
        __syncthreads();
        for (int u = t; u < 16*48; u += 256) {
            int e = u / 48, j = u - 48*(u/48);
            float acc = eb2[j];
            #pragma unroll 4
            for (int i = 0; i < HID; i++) acc += l1g[e][i]*ew2[i*48 + j];
            gg[e][j] = acc;
        }
        __syncthreads();
        for (int u = t; u < 16*80; u += 256) {
            int e = u / 80, cc = u - 80*(u/80);
            gexp[(e0 + e)*OUT_DIM + cc] = (cc < M0O) ? gg[e][cc] : gg[e][M0O + (cc - M0O)/3];
        }
    }
}

// ---------------- big GEMM: tpwE[e, 4608] = hiddenE[e,128] @ rw2 + rb2 (fp16 out) ----------------
__global__ __launch_bounds__(256) void k_tpw(
    const float* __restrict__ hiddenE, const float* __restrict__ rw2, const float* __restrict__ rb2,
    __half* __restrict__ tpwE)
{
    int col0 = blockIdx.x * 128;
    int row0 = blockIdx.y * 64;
    int t = threadIdx.x;
    __shared__ float As[64][33];
    __shared__ float Bs[32][128];
    float4 acc[8];
    for (int j = 0; j < 8; j++) acc[j] = make_float4(0,0,0,0);
    int tc = t & 31, tr = t >> 5;
    for (int k0 = 0; k0 < HID; k0 += 32) {
        for (int p = 0; p < 2; p++) {
            int idx = t + 256*p;
            int rr = idx >> 3, k4 = idx & 7;
            float4 hv = *(const float4*)&hiddenE[(row0 + rr)*HID + k0 + k4*4];
            As[rr][k4*4]   = hv.x; As[rr][k4*4+1] = hv.y;
            As[rr][k4*4+2] = hv.z; As[rr][k4*4+3] = hv.w;
        }
        for (int p = 0; p < 4; p++) {
            int idx = t + 256*p;
            int kk = idx >> 5, c4 = idx & 31;
            *(float4*)&Bs[kk][c4*4] = *(const float4*)&rw2[(k0 + kk)*WNUM + col0 + c4*4];
        }
        __syncthreads();
        for (int kk = 0; kk < 32; kk++) {
            float4 bv = *(float4*)&Bs[kk][tc*4];
            #pragma unroll
            for (int j = 0; j < 8; j++) {
                float a = As[tr*8 + j][kk];
                acc[j].x += a*bv.x; acc[j].y += a*bv.y; acc[j].z += a*bv.z; acc[j].w += a*bv.w;
            }
        }
        __syncthreads();
    }
    float4 bias = *(const float4*)&rb2[col0 + tc*4];
    for (int j = 0; j < 8; j++) {
        int r = row0 + tr*8 + j;
        __half2* d2 = (__half2*)&tpwE[(long)r*WNUM + col0 + tc*4];
        d2[0] = __floats2half2_rn(acc[j].x + bias.x, acc[j].y + bias.y);
        d2[1] = __floats2half2_rn(acc[j].z + bias.z, acc[j].w + bias.w);
    }
}

// ---------------- q layers 2-3 ----------------
__global__ __launch_bounds__(256) void k_q23(
    const float* __restrict__ habs1, const float* __restrict__ ec, const float* __restrict__ qb1,
    const float* __restrict__ qw2, const float* __restrict__ qb2,
    const float* __restrict__ qw3, const float* __restrict__ qb3,
    float* __restrict__ qmat)
{
    int r0 = blockIdx.x * 16;
    int t = threadIdx.x;
    __shared__ float l1S[16][128];
    __shared__ float l2S[16][128];
    for (int p = 0; p < 2; p++) {
        int idx = t + 256*p;
        int rr = idx >> 5, i4 = idx & 31;
        int be = r0 + rr; int b = be >> 8; int e = be & 255;
        float4 ha = *(const float4*)&habs1[b*HID + i4*4];
        float4 ev = *(const float4*)&ec[e*HID + i4*4];
        float4 qb = *(const float4*)&qb1[i4*4];
        l1S[rr][i4*4]   = silu_f(ha.x + ev.x + qb.x);
        l1S[rr][i4*4+1] = silu_f(ha.y + ev.y + qb.y);
        l1S[rr][i4*4+2] = silu_f(ha.z + ev.z + qb.z);
        l1S[rr][i4*4+3] = silu_f(ha.w + ev.w + qb.w);
    }
    __syncthreads();
    int r = t >> 4, c0 = (t & 15)*8;
    {
        float4 a0 = *(const float4*)&qb2[c0];
        float4 a1 = *(const float4*)&qb2[c0 + 4];
        #pragma unroll 4
        for (int i = 0; i < HID; i++) {
            float a = l1S[r][i];
            float4 w0 = *(const float4*)&qw2[i*HID + c0];
            float4 w1 = *(const float4*)&qw2[i*HID + c0 + 4];
            a0.x += a*w0.x; a0.y += a*w0.y; a0.z += a*w0.z; a0.w += a*w0.w;
            a1.x += a*w1.x; a1.y += a*w1.y; a1.z += a*w1.z; a1.w += a*w1.w;
        }
        l2S[r][c0]   = silu_f(a0.x); l2S[r][c0+1] = silu_f(a0.y);
        l2S[r][c0+2] = silu_f(a0.z); l2S[r][c0+3] = silu_f(a0.w);
        l2S[r][c0+4] = silu_f(a1.x); l2S[r][c0+5] = silu_f(a1.y);
        l2S[r][c0+6] = silu_f(a1.z); l2S[r][c0+7] = silu_f(a1.w);
    }
    __syncthreads();
    {
        float4 a0 = *(const float4*)&qb3[c0];
        float4 a1 = *(const float4*)&qb3[c0 + 4];
        #pragma unroll 4
        for (int i = 0; i < HID; i++) {
            float a = l2S[r][i];
            float4 w0 = *(const float4*)&qw3[i*HID + c0];
            float4 w1 = *(const float4*)&qw3[i*HID + c0 + 4];
            a0.x += a*w0.x; a0.y += a*w0.y; a0.z += a*w0.z; a0.w += a*w0.w;
            a1.x += a*w1.x; a1.y += a*w1.y; a1.z += a*w1.z; a1.w += a*w1.w;
        }
        *(float4*)&qmat[(r0 + r)*LAT + c0] = a0;
        *(float4*)&qmat[(r0 + r)*LAT + c0 + 4] = a1;
    }
}

// ---------------- tensor product per edge -> virr ----------------
__global__ __launch_bounds__(128) void k_tp(
    const float* __restrict__ h_full, const __half* __restrict__ tpwE,
    const int* __restrict__ att_dst,
    const float* __restrict__ envE, const float* __restrict__ y1E,
    float* __restrict__ virr)
{
    int e = blockIdx.x; int t = threadIdx.x;
    int f = att_dst[e];
    __shared__ float x0[M0I];
    __shared__ float x1f[M1I*3];
    __shared__ float xy[M1I];
    __shared__ float y1s[3];
    const float* hf = h_full + f*NODE_DIM;
    if (t < M0I) x0[t] = hf[t];
    if (t < M1I*3) x1f[t] = hf[M0I + t];
    if (t < 3) y1s[t] = y1E[3*e + t];
    __syncthreads();
    if (t < M1I) xy[t] = x1f[3*t]*y1s[0] + x1f[3*t+1]*y1s[1] + x1f[3*t+2]*y1s[2];
    __syncthreads();
    float scale = envE[e];
    const __half* w = tpwE + (long)e*WNUM;
    const float alpha = 0.10206207261596575f;  // 1/sqrt(96)
    const float cc = 0.5773502691896258f;      // 1/sqrt(3)
    if (t < M0O) {
        float t00 = 0.f, t11 = 0.f;
        #pragma unroll 4
        for (int i = 0; i < M0I; i++) t00 += x0[i]*__half2float(w[i*M0O + t]);
        #pragma unroll 4
        for (int i = 0; i < M1I; i++) t11 += xy[i]*__half2float(w[SEG3 + i*M0O + t]);
        virr[f*OUT_DIM + t] = alpha*(t00 + cc*t11)*scale;
    } else if (t < M0O + 3*M1O) {
        int idx = t - M0O; int o = idx/3, m = idx - 3*o;
        float t01 = 0.f, t10 = 0.f;
        #pragma unroll 4
        for (int i = 0; i < M0I; i++) t01 += x0[i]*__half2float(w[SEG1 + i*M1O + o]);
        #pragma unroll 4
        for (int i = 0; i < M1I; i++) t10 += x1f[i*3 + m]*__half2float(w[SEG2 + i*M1O + o]);
        virr[f*OUT_DIM + t] = alpha*cc*(t01*y1s[m] + t10)*scale;
    }
}

// ---------------- attention: (b, 8e) blocks ----------------
__global__ __launch_bounds__(256) void k_att(
    const float* __restrict__ qmat, const float* __restrict__ kmat, const int* __restrict__ inv,
    const float* __restrict__ virr, const float* __restrict__ gexp,
    float* __restrict__ invm)
{
    int b  = blockIdx.x >> 5;
    int e0 = (blockIdx.x & 31) * 8;
    int t = threadIdx.x;
    __shared__ float qS[8][132];
    __shared__ float vS[NN][84];
    __shared__ float aS[8][100];
    __shared__ float gS[8][84];
    __shared__ float ocS[8][84];
    __shared__ float mS[NN];

    for (int p = 0; p < 4; p++) {
        int idx = t + 256*p; int el = idx >> 7, i = idx & 127;
        qS[el][i] = qmat[(b*NE + e0 + el)*LAT + i];
    }
    for (int idx = t; idx < NN*OUT_DIM; idx += 256) {
        int n = idx / OUT_DIM, cc = idx - n*OUT_DIM;
        // mask-zero staging: unattended virr rows are never written (poison) -> zero them here
        vS[n][cc] = ((unsigned)inv[b*NN + n] < E_ATT) ? virr[(b*NN + n)*OUT_DIM + cc] : 0.0f;
    }
    for (int idx = t; idx < 8*OUT_DIM; idx += 256) {
        int el = idx / OUT_DIM, cc = idx - el*OUT_DIM;
        gS[el][cc] = gexp[(e0 + el)*OUT_DIM + cc];
    }
    if (t < NN) mS[t] = ((unsigned)inv[b*NN + t] < E_ATT) ? 1.0f : 0.0f;
    __syncthreads();

    {
        int el = t >> 5;
        int ng = t & 31;
        float a0 = 0.f, a1 = 0.f, a2 = 0.f;
        const float* k0p = kmat + (b*NN + ng)*LAT;
        const float* k1p = kmat + (b*NN + ng + 32)*LAT;
        const float* k2p = kmat + (b*NN + ng + 64)*LAT;
        #pragma unroll 4
        for (int i = 0; i < LAT; i += 4) {
            float4 qv = *(float4*)&qS[el][i];
            float4 k0 = *(const float4*)&k0p[i];
            float4 k1 = *(const float4*)&k1p[i];
            float4 k2 = *(const float4*)&k2p[i];
            a0 += qv.x*k0.x + qv.y*k0.y + qv.z*k0.z + qv.w*k0.w;
            a1 += qv.x*k1.x + qv.y*k1.y + qv.z*k1.z + qv.w*k1.w;
            a2 += qv.x*k2.x + qv.y*k2.y + qv.z*k2.z + qv.w*k2.w;
        }
        const float scale = 0.04419417382415922f;  // (1/HEADS)*HD^-0.5
        aS[el][ng]      = (mS[ng]      != 0.f) ? a0*scale : -1e9f;
        aS[el][ng + 32] = (mS[ng + 32] != 0.f) ? a1*scale : -1e9f;
        aS[el][ng + 64] = (mS[ng + 64] != 0.f) ? a2*scale : -1e9f;
    }
    __syncthreads();

    if (t < 8) {
        float mx = -INFINITY;
        for (int n = 0; n < NN; n++) mx = fmaxf(mx, aS[t][n]);
        float sm = 0.f;
        for (int n = 0; n < NN; n++) { float ex = expf(aS[t][n] - mx); aS[t][n] = ex; sm += ex; }
        float s2 = 0.f;
        for (int n = 0; n < NN; n++) {
            float a = (mS[n] != 0.f) ? aS[t][n]/sm : 0.f;
            aS[t][n] = a; s2 += a;
        }
        float is = 1.0f / fmaxf(s2, 1e-8f);
        for (int n = 0; n < NN; n++) aS[t][n] *= is;
    }
    __syncthreads();

    for (int u = t; u < 8*OUT_DIM; u += 256) {
        int el = u / OUT_DIM, cc = u - el*OUT_DIM;
        float acc = 0.f;
        #pragma unroll 4
        for (int n = 0; n < NN; n++) acc += aS[el][n]*vS[n][cc];
        ocS[el][cc] = acc * gS[el][cc];
    }
    __syncthreads();

    for (int u = t; u < 8*INVD; u += 256) {
        int el = u / INVD, j = u - el*INVD;
        float val;
        if (j < M0O) val = ocS[el][j];
        else {
            int o = j - M0O;
            float x = ocS[el][M0O + 3*o], y = ocS[el][M0O + 3*o + 1], zz = ocS[el][M0O + 3*o + 2];
            val = sqrtf(x*x + y*y + zz*zz + 1e-12f);
        }
        invm[(b*NE + e0 + el)*INVD + j] = val;
    }
}

// ---------------- final MLP: 4096 rows x (48->128->128->128), 8 rows/block ----------------
__global__ __launch_bounds__(256) void k_final(
    const float* __restrict__ invm,
    const float* __restrict__ ow1, const float* __restrict__ ob1,
    const float* __restrict__ ow2, const float* __restrict__ ob2,
    const float* __restrict__ ow3, const float* __restrict__ ob3,
    float* __restrict__ out)
{
    int r0 = blockIdx.x * 8;
    int t = threadIdx.x;
    int r = t >> 5, c0 = (t & 31)*4;
    __shared__ float inS[8][INVD];
    __shared__ float l1S[8][HID];
    __shared__ float l2S[8][HID];
    for (int idx = t; idx < 8*INVD; idx += 256) {
        int rr = idx / INVD, j = idx - rr*INVD;
        inS[rr][j] = invm[(r0 + rr)*INVD + j];
    }
    __syncthreads();
    {
        float4 a0 = *(const float4*)&ob1[c0];
        float4 a1 = make_float4(0,0,0,0);
        #pragma unroll 8
        for (int i = 0; i < INVD; i += 2) {
            float x0v = inS[r][i], x1v = inS[r][i+1];
            float4 w0 = *(const float4*)&ow1[i*HID + c0];
            float4 w1 = *(const float4*)&ow1[(i+1)*HID + c0];
            a0.x += x0v*w0.x; a0.y += x0v*w0.y; a0.z += x0v*w0.z; a0.w += x0v*w0.w;
            a1.x += x1v*w1.x; a1.y += x1v*w1.y; a1.z += x1v*w1.z; a1.w += x1v*w1.w;
        }
        l1S[r][c0]   = silu_f(a0.x + a1.x); l1S[r][c0+1] = silu_f(a0.y + a1.y);
        l1S[r][c0+2] = silu_f(a0.z + a1.z); l1S[r][c0+3] = silu_f(a0.w + a1.w);
    }
    __syncthreads();
    {
        float4 a0 = *(const float4*)&ob2[c0];
        float4 a1 = make_float4(0,0,0,0);
        #pragma unroll 8
        for (int i = 0; i < HID; i += 2) {
            float x0v = l1S[r][i], x1v = l1S[r][i+1];
            float4 w0 = *(const float4*)&ow2[i*HID + c0];
            float4 w1 = *(const float4*)&ow2[(i+1)*HID + c0];
            a0.x += x0v*w0.x; a0.y += x0v*w0.y; a0.z += x0v*w0.z; a0.w += x0v*w0.w;
            a1.x += x1v*w1.x; a1.y += x1v*w1.y; a1.z += x1v*w1.z; a1.w += x1v*w1.w;
        }
        l2S[r][c0]   = silu_f(a0.x + a1.x); l2S[r][c0+1] = silu_f(a0.y + a1.y);
        l2S[r][c0+2] = silu_f(a0.z + a1.z); l2S[r][c0+3] = silu_f(a0.w + a1.w);
    }
    __syncthreads();
    {
        float4 a0 = *(const float4*)&ob3[c0];
        float4 a1 = make_float4(0,0,0,0);
        #pragma unroll 8
        for (int i = 0; i < HID; i += 2) {
            float x0v = l2S[r][i], x1v = l2S[r][i+1];
            float4 w0 = *(const float4*)&ow3[i*HID + c0];
            float4 w1 = *(const float4*)&ow3[(i+1)*HID + c0];
            a0.x += x0v*w0.x; a0.y += x0v*w0.y; a0.z += x0v*w0.z; a0.w += x0v*w0.w;
            a1.x += x1v*w1.x; a1.y += x1v*w1.y; a1.z += x1v*w1.z; a1.w += x1v*w1.w;
        }
        float4 o;
        o.x = a0.x + a1.x; o.y = a0.y + a1.y; o.z = a0.z + a1.z; o.w = a0.w + a1.w;
        *(float4*)&out[(r0 + r)*LAT + c0] = o;
    }
}

extern "C" void kernel_launch(void* const* d_in, const int* in_sizes, int n_in,
                              void* d_out, int out_size, void* d_ws, size_t ws_size,
                              hipStream_t stream) {
    const float* h        = (const float*)d_in[0];
    const float* h_full   = (const float*)d_in[1];
    const float* e_feat   = (const float*)d_in[2];
    const float* att_dist = (const float*)d_in[3];
    const float* att_vec  = (const float*)d_in[4];
    const float* z_emb    = (const float*)d_in[5];
    const float* rw1 = (const float*)d_in[6];  const float* rb1 = (const float*)d_in[7];
    const float* rw2 = (const float*)d_in[8];  const float* rb2 = (const float*)d_in[9];
    const float* ew1 = (const float*)d_in[10]; const float* eb1 = (const float*)d_in[11];
    const float* ew2 = (const float*)d_in[12]; const float* eb2 = (const float*)d_in[13];
    const float* qw1 = (const float*)d_in[14]; const float* qb1 = (const float*)d_in[15];
    const float* qw2 = (const float*)d_in[16]; const float* qb2 = (const float*)d_in[17];
    const float* qw3 = (const float*)d_in[18]; const float* qb3 = (const float*)d_in[19];
    const float* kw1 = (const float*)d_in[20]; const float* kb1 = (const float*)d_in[21];
    const float* kw2 = (const float*)d_in[22]; const float* kb2 = (const float*)d_in[23];
    const float* kw3 = (const float*)d_in[24]; const float* kb3 = (const float*)d_in[25];
    const float* ow1 = (const float*)d_in[26]; const float* ob1 = (const float*)d_in[27];
    const float* ow2 = (const float*)d_in[28]; const float* ob2 = (const float*)d_in[29];
    const float* ow3 = (const float*)d_in[30]; const float* ob3 = (const float*)d_in[31];
    const int* z        = (const int*)d_in[32];
    const int* absorber = (const int*)d_in[34];
    const int* att_dst  = (const int*)d_in[35];

    float* ws = (float*)d_ws;
    int*   inv     = (int*)ws;                    // 1536
    float* y1E     = ws + 1536;                   // 3072
    float* envE    = ws + 4608;                   // 1024
    float* hiddenE = ws + 5632;                   // 131072 (1024x128)
    float* kmat    = ws + 136704;                 // 196608 (1536x128)
    float* qmat    = ws + 333312;                 // 524288 (4096x128)
    float* gexp    = ws + 857600;                 // 20480
    float* virr    = ws + 878080;                 // 122880 (1536x80)
    float* habs1   = ws + 1000960;                // 2048
    float* ec      = ws + 1003008;                // 32768
    float* invm    = ws + 1035776;                // 196608 (4096x48)
    __half* tpwE   = (__half*)(ws + 1232384);     // 1024*4608 halves (9.4 MB)

    float* out = (float*)d_out;

    k_prep<<<1, 1024, 0, stream>>>(att_dst, att_dist, att_vec, inv, y1E, envE);
    k_stage1<<<STAGE1_BLKS, 256, 0, stream>>>(h, z_emb, z, absorber, e_feat, inv, att_dist,
                                              rw1, rb1, kw1, kb1, kw2, kb2, kw3, kb3,
                                              qw1, ew1, eb1, ew2, eb2,
                                              hiddenE, kmat, ec, habs1, gexp);
    k_tpw<<<dim3(WNUM/128, E_ATT/64), 256, 0, stream>>>(hiddenE, rw2, rb2, tpwE);
    k_q23<<<BB*NE/16, 256, 0, stream>>>(habs1, ec, qb1, qw2, qb2, qw3, qb3, qmat);
    k_tp<<<E_ATT, 128, 0, stream>>>(h_full, tpwE, att_dst, envE, y1E, virr);
    k_att<<<BB*32, 256, 0, stream>>>(qmat, kmat, inv, virr, gexp, invm);
    k_final<<<BB*NE/8, 256, 0, stream>>>(invm, ow1, ob1, ow2, ob2, ow3, ob3, out);
}

// Round 6
// 269.012 us; speedup vs baseline: 2.6121x; 1.0945x over previous
//
#include <hip/hip_runtime.h>
#include <hip/hip_fp16.h>
#include <math.h>

#define BB 16
#define NN 96
#define NE 256
#define FF (BB*NN)      // 1536
#define ATOM 128
#define EDIM 16
#define HID 128
#define LAT 128
#define RBFN 16
#define CUTOFF 5.0f
#define ZEMB 32
#define E_ATT 1024
#define M0I 64
#define M1I 32
#define M0O 32
#define M1O 16
#define NODE_DIM 160
#define OUT_DIM 80
#define INVD 48
#define WNUM 4608
#define SEG1 2048
#define SEG2 3072
#define SEG3 3584

#define NODE_BLKS (FF/8)   // 192
#define EC_BLKS 16
#define HABS_BLKS 2
#define GATE_BLKS 16
#define STAGE1_BLKS (NODE_BLKS + EC_BLKS + HABS_BLKS + GATE_BLKS)  // 226

__device__ __forceinline__ float silu_f(float x) { return x / (1.0f + expf(-x)); }

// ---------------- prep: blocks 0..119 zero virr; block 120: inv init + scatter + y1/env ----------------
__global__ __launch_bounds__(256) void k_prep(
    const int* __restrict__ att_dst, const float* __restrict__ att_dist,
    const float* __restrict__ att_vec,
    int* __restrict__ inv, float* __restrict__ y1E, float* __restrict__ envE,
    float* __restrict__ virr)
{
    int blk = blockIdx.x;
    int t = threadIdx.x;
    if (blk < 120) {
        // zero virr: 1536*80 floats = 30720 float4 = 120 blocks * 256
        int i = blk*256 + t;
        float4 zz = make_float4(0.f, 0.f, 0.f, 0.f);
        ((float4*)virr)[i] = zz;
        return;
    }
    // block 120: inv = -1 (1536 = 6*256)
    for (int p = 0; p < 6; p++) inv[t + 256*p] = -1;
    // y1/env for 1024 edges
    for (int p = 0; p < 4; p++) {
        int e = t + 256*p;
        float d = att_dist[e];
        envE[e] = (d < CUTOFF) ? 0.5f*(cosf(3.14159265358979323846f*d/CUTOFF) + 1.0f) : 0.0f;
        float vx = att_vec[3*e], vy = att_vec[3*e+1], vz = att_vec[3*e+2];
        float nrm = sqrtf(vx*vx + vy*vy + vz*vz);
        float is = 1.0f / fmaxf(nrm, 1e-8f);
        const float s3 = 1.7320508075688772f;
        y1E[3*e]   = s3*vx*is;
        y1E[3*e+1] = s3*vy*is;
        y1E[3*e+2] = s3*vz*is;
    }
    __syncthreads();
    for (int p = 0; p < 4; p++) { int e = t + 256*p; inv[att_dst[e]] = e; }
}

// ---------------- stage1 mega-kernel (unchanged from R5) ----------------
__global__ __launch_bounds__(256) void k_stage1(
    const float* __restrict__ h, const float* __restrict__ z_emb, const int* __restrict__ z,
    const int* __restrict__ absorber, const float* __restrict__ e_feat,
    const int* __restrict__ inv, const float* __restrict__ att_dist,
    const float* __restrict__ rw1, const float* __restrict__ rb1,
    const float* __restrict__ kw1, const float* __restrict__ kb1,
    const float* __restrict__ kw2, const float* __restrict__ kb2,
    const float* __restrict__ kw3, const float* __restrict__ kb3,
    const float* __restrict__ qw1,
    const float* __restrict__ ew1, const float* __restrict__ eb1,
    const float* __restrict__ ew2, const float* __restrict__ eb2,
    float* __restrict__ hiddenE, float* __restrict__ kmatw,
    float* __restrict__ ecw, float* __restrict__ habs1w, float* __restrict__ gexp)
{
    __shared__ float smem[3488];
    int blk = blockIdx.x;
    int t = threadIdx.x;

    if (blk < NODE_BLKS) {
        float (*sin1)[180] = (float(*)[180])smem;
        float (*l1S)[128]  = (float(*)[128])(smem + 1440);
        float (*l2S)[128]  = (float(*)[128])(smem + 1440 + 1024);
        int f0 = blk * 8;
        {
            int n = t >> 5, i4 = t & 31;
            *(float4*)&sin1[n][i4*4] = *(const float4*)&h[(f0 + n)*ATOM + i4*4];
        }
        {
            int n = t >> 5, j = t & 31;
            sin1[n][ATOM + j] = z_emb[z[f0 + n]*ZEMB + j];
        }
        if (t < 128) {
            int n = t >> 4, j = t & 15;
            int e = inv[f0 + n];
            float d = ((unsigned)e < E_ATT) ? att_dist[e] : 0.0f;
            const float delta = CUTOFF / (RBFN - 1);
            float diff = d - j*delta;
            sin1[n][ATOM + ZEMB + 1 + j] = expf(-diff*diff / (2.0f*delta*delta));
        }
        if (t < 8) {
            int f = f0 + t;
            int b = f / NN, nn = f - b*NN;
            sin1[t][ATOM + ZEMB] = (absorber[b] == nn) ? 1.0f : 0.0f;
        }
        __syncthreads();
        int r = t >> 5, c0 = (t & 31)*4;
        int e = inv[f0 + r];
        bool att_ = ((unsigned)e < E_ATT);
        if (att_) {
            float4 a0 = *(const float4*)&rb1[c0];
            float4 a1 = make_float4(0,0,0,0);
            #pragma unroll 8
            for (int i = 0; i < 48; i += 2) {
                float x0v = sin1[r][ATOM + i], x1v = sin1[r][ATOM + i + 1];
                float4 w0 = *(const float4*)&rw1[i*HID + c0];
                float4 w1 = *(const float4*)&rw1[(i+1)*HID + c0];
                a0.x += x0v*w0.x; a0.y += x0v*w0.y; a0.z += x0v*w0.z; a0.w += x0v*w0.w;
                a1.x += x1v*w1.x; a1.y += x1v*w1.y; a1.z += x1v*w1.z; a1.w += x1v*w1.w;
            }
            {
                float x0v = sin1[r][ATOM + 48];
                float4 w0 = *(const float4*)&rw1[48*HID + c0];
                a0.x += x0v*w0.x; a0.y += x0v*w0.y; a0.z += x0v*w0.z; a0.w += x0v*w0.w;
            }
            float4 o;
            o.x = silu_f(a0.x + a1.x); o.y = silu_f(a0.y + a1.y);
            o.z = silu_f(a0.z + a1.z); o.w = silu_f(a0.w + a1.w);
            *(float4*)&hiddenE[e*HID + c0] = o;
        }
        {
            float4 a0 = *(const float4*)&kb1[c0];
            float4 a1 = make_float4(0,0,0,0);
            #pragma unroll 8
            for (int i = 0; i < 176; i += 2) {
                float x0v = sin1[r][i], x1v = sin1[r][i + 1];
                float4 w0 = *(const float4*)&kw1[i*HID + c0];
                float4 w1 = *(const float4*)&kw1[(i+1)*HID + c0];
                a0.x += x0v*w0.x; a0.y += x0v*w0.y; a0.z += x0v*w0.z; a0.w += x0v*w0.w;
                a1.x += x1v*w1.x; a1.y += x1v*w1.y; a1.z += x1v*w1.z; a1.w += x1v*w1.w;
            }
            {
                float x0v = sin1[r][176];
                float4 w0 = *(const float4*)&kw1[176*HID + c0];
                a0.x += x0v*w0.x; a0.y += x0v*w0.y; a0.z += x0v*w0.z; a0.w += x0v*w0.w;
            }
            l1S[r][c0]   = silu_f(a0.x + a1.x); l1S[r][c0+1] = silu_f(a0.y + a1.y);
            l1S[r][c0+2] = silu_f(a0.z + a1.z); l1S[r][c0+3] = silu_f(a0.w + a1.w);
        }
        __syncthreads();
        {
            float4 a0 = *(const float4*)&kb2[c0];
            float4 a1 = make_float4(0,0,0,0);
            #pragma unroll 8
            for (int i = 0; i < HID; i += 2) {
                float x0v = l1S[r][i], x1v = l1S[r][i + 1];
                float4 w0 = *(const float4*)&kw2[i*HID + c0];
                float4 w1 = *(const float4*)&kw2[(i+1)*HID + c0];
                a0.x += x0v*w0.x; a0.y += x0v*w0.y; a0.z += x0v*w0.z; a0.w += x0v*w0.w;
                a1.x += x1v*w1.x; a1.y += x1v*w1.y; a1.z += x1v*w1.z; a1.w += x1v*w1.w;
            }
            l2S[r][c0]   = silu_f(a0.x + a1.x); l2S[r][c0+1] = silu_f(a0.y + a1.y);
            l2S[r][c0+2] = silu_f(a0.z + a1.z); l2S[r][c0+3] = silu_f(a0.w + a1.w);
        }
        __syncthreads();
        {
            float4 a0 = *(const float4*)&kb3[c0];
            float4 a1 = make_float4(0,0,0,0);
            #pragma unroll 8
            for (int i = 0; i < HID; i += 2) {
                float x0v = l2S[r][i], x1v = l2S[r][i + 1];
                float4 w0 = *(const float4*)&kw3[i*HID + c0];
                float4 w1 = *(const float4*)&kw3[(i+1)*HID + c0];
                a0.x += x0v*w0.x; a0.y += x0v*w0.y; a0.z += x0v*w0.z; a0.w += x0v*w0.w;
                a1.x += x1v*w1.x; a1.y += x1v*w1.y; a1.z += x1v*w1.z; a1.w += x1v*w1.w;
            }
            float4 o;
            o.x = a0.x + a1.x; o.y = a0.y + a1.y; o.z = a0.z + a1.z; o.w = a0.w + a1.w;
            *(float4*)&kmatw[(f0 + r)*HID + c0] = o;
        }
    } else if (blk < NODE_BLKS + EC_BLKS) {
        float (*ef)[16] = (float(*)[16])smem;
        int e0 = (blk - NODE_BLKS) * 16;
        { int e = t >> 4, i = t & 15; ef[e][i] = e_feat[(e0 + e)*EDIM + i]; }
        __syncthreads();
        int r = t >> 4, c0 = (t & 15)*8;
        float4 a0 = make_float4(0,0,0,0), a1 = a0;
        #pragma unroll
        for (int i = 0; i < EDIM; i++) {
            float a = ef[r][i];
            float4 w0 = *(const float4*)&qw1[(ATOM + i)*HID + c0];
            float4 w1 = *(const float4*)&qw1[(ATOM + i)*HID + c0 + 4];
            a0.x += a*w0.x; a0.y += a*w0.y; a0.z += a*w0.z; a0.w += a*w0.w;
            a1.x += a*w1.x; a1.y += a*w1.y; a1.z += a*w1.z; a1.w += a*w1.w;
        }
        *(float4*)&ecw[(e0 + r)*HID + c0] = a0;
        *(float4*)&ecw[(e0 + r)*HID + c0 + 4] = a1;
    } else if (blk < NODE_BLKS + EC_BLKS + HABS_BLKS) {
        float (*hr)[128] = (float(*)[128])smem;
        int b0 = (blk - NODE_BLKS - EC_BLKS) * 8;
        {
            int r = t >> 5, i4 = t & 31;
            int b = b0 + r;
            int a = absorber[b];
            *(float4*)&hr[r][i4*4] = *(const float4*)&h[(b*NN + a)*ATOM + i4*4];
        }
        __syncthreads();
        int r = t >> 5, c0 = (t & 31)*4;
        float4 a0 = make_float4(0,0,0,0), a1 = a0;
        #pragma unroll 8
        for (int i = 0; i < ATOM; i += 2) {
            float x0v = hr[r][i], x1v = hr[r][i+1];
            float4 w0 = *(const float4*)&qw1[i*HID + c0];
            float4 w1 = *(const float4*)&qw1[(i+1)*HID + c0];
            a0.x += x0v*w0.x; a0.y += x0v*w0.y; a0.z += x0v*w0.z; a0.w += x0v*w0.w;
            a1.x += x1v*w1.x; a1.y += x1v*w1.y; a1.z += x1v*w1.z; a1.w += x1v*w1.w;
        }
        float4 o;
        o.x = a0.x + a1.x; o.y = a0.y + a1.y; o.z = a0.z + a1.z; o.w = a0.w + a1.w;
        *(float4*)&habs1w[(b0 + r)*HID + c0] = o;
    } else {
        float (*ef)[16]   = (float(*)[16])smem;
        float (*l1g)[128] = (float(*)[128])(smem + 256);
        float (*gg)[48]   = (float(*)[48])(smem + 256 + 2048);
        int e0 = (blk - NODE_BLKS - EC_BLKS - HABS_BLKS) * 16;
        { int e = t >> 4, i = t & 15; ef[e][i] = e_feat[(e0 + e)*EDIM + i]; }
        __syncthreads();
        int r = t >> 4, c0 = (t & 15)*8;
        {
            float4 a0 = *(const float4*)&eb1[c0];
            float4 a1 = *(const float4*)&eb1[c0 + 4];
            #pragma unroll
            for (int i = 0; i < EDIM; i++) {
                float a = ef[r][i];
                float4 w0 = *(const float4*)&ew1[i*HID + c0];
                float4 w1 = *(const float4*)&ew1[i*HID + c0 + 4];
                a0.x += a*w0.x; a0.y += a*w0.y; a0.z += a*w0.z; a0.w += a*w0.w;
                a1.x += a*w1.x; a1.y += a*w1.y; a1.z += a*w1.z; a1.w += a*w1.w;
            }
            l1g[r][c0]   = silu_f(a0.x); l1g[r][c0+1] = silu_f(a0.y);
            l1g[r][c0+2] = silu_f(a0.z); l1g[r][c0+3] = silu_f(a0.w);
            l1g[r][c0+4] = silu_f(a1.x); l1g[r][c0+5] = silu_f(a1.y);
            l1g[r][c0+6] = silu_f(a1.z); l1g[r][c0+7] = silu_f(a1.w);
        }
        __syncthreads();
        for (int u = t; u < 16*48; u += 256) {
            int e = u / 48, j = u - 48*(u/48);
            float acc = eb2[j];
            #pragma unroll 4
            for (int i = 0; i < HID; i++) acc += l1g[e][i]*ew2[i*48 + j];
            gg[e][j] = acc;
        }
        __syncthreads();
        for (int u = t; u < 16*80; u += 256) {
            int e = u / 80, cc = u - 80*(u/80);
            gexp[(e0 + e)*OUT_DIM + cc] = (cc < M0O) ? gg[e][cc] : gg[e][M0O + (cc - M0O)/3];
        }
    }
}

// ---------------- big GEMM: tpwE[e, 4608] = hiddenE[e,128] @ rw2 + rb2 (fp16 out) ----------------
__global__ __launch_bounds__(256) void k_tpw(
    const float* __restrict__ hiddenE, const float* __restrict__ rw2, const float* __restrict__ rb2,
    __half* __restrict__ tpwE)
{
    int col0 = blockIdx.x * 128;
    int row0 = blockIdx.y * 64;
    int t = threadIdx.x;
    __shared__ float As[64][33];
    __shared__ float Bs[32][128];
    float4 acc[8];
    for (int j = 0; j < 8; j++) acc[j] = make_float4(0,0,0,0);
    int tc = t & 31, tr = t >> 5;
    for (int k0 = 0; k0 < HID; k0 += 32) {
        for (int p = 0; p < 2; p++) {
            int idx = t + 256*p;
            int rr = idx >> 3, k4 = idx & 7;
            float4 hv = *(const float4*)&hiddenE[(row0 + rr)*HID + k0 + k4*4];
            As[rr][k4*4]   = hv.x; As[rr][k4*4+1] = hv.y;
            As[rr][k4*4+2] = hv.z; As[rr][k4*4+3] = hv.w;
        }
        for (int p = 0; p < 4; p++) {
            int idx = t + 256*p;
            int kk = idx >> 5, c4 = idx & 31;
            *(float4*)&Bs[kk][c4*4] = *(const float4*)&rw2[(k0 + kk)*WNUM + col0 + c4*4];
        }
        __syncthreads();
        for (int kk = 0; kk < 32; kk++) {
            float4 bv = *(float4*)&Bs[kk][tc*4];
            #pragma unroll
            for (int j = 0; j < 8; j++) {
                float a = As[tr*8 + j][kk];
                acc[j].x += a*bv.x; acc[j].y += a*bv.y; acc[j].z += a*bv.z; acc[j].w += a*bv.w;
            }
        }
        __syncthreads();
    }
    float4 bias = *(const float4*)&rb2[col0 + tc*4];
    for (int j = 0; j < 8; j++) {
        int r = row0 + tr*8 + j;
        __half2* d2 = (__half2*)&tpwE[(long)r*WNUM + col0 + tc*4];
        d2[0] = __floats2half2_rn(acc[j].x + bias.x, acc[j].y + bias.y);
        d2[1] = __floats2half2_rn(acc[j].z + bias.z, acc[j].w + bias.w);
    }
}

// ---------------- q layers 2-3 (unchanged from R5) ----------------
__global__ __launch_bounds__(256) void k_q23(
    const float* __restrict__ habs1, const float* __restrict__ ec, const float* __restrict__ qb1,
    const float* __restrict__ qw2, const float* __restrict__ qb2,
    const float* __restrict__ qw3, const float* __restrict__ qb3,
    float* __restrict__ qmat)
{
    int r0 = blockIdx.x * 16;
    int t = threadIdx.x;
    __shared__ float l1S[16][128];
    __shared__ float l2S[16][128];
    for (int p = 0; p < 2; p++) {
        int idx = t + 256*p;
        int rr = idx >> 5, i4 = idx & 31;
        int be = r0 + rr; int b = be >> 8; int e = be & 255;
        float4 ha = *(const float4*)&habs1[b*HID + i4*4];
        float4 ev = *(const float4*)&ec[e*HID + i4*4];
        float4 qb = *(const float4*)&qb1[i4*4];
        l1S[rr][i4*4]   = silu_f(ha.x + ev.x + qb.x);
        l1S[rr][i4*4+1] = silu_f(ha.y + ev.y + qb.y);
        l1S[rr][i4*4+2] = silu_f(ha.z + ev.z + qb.z);
        l1S[rr][i4*4+3] = silu_f(ha.w + ev.w + qb.w);
    }
    __syncthreads();
    int r = t >> 4, c0 = (t & 15)*8;
    {
        float4 a0 = *(const float4*)&qb2[c0];
        float4 a1 = *(const float4*)&qb2[c0 + 4];
        #pragma unroll 4
        for (int i = 0; i < HID; i++) {
            float a = l1S[r][i];
            float4 w0 = *(const float4*)&qw2[i*HID + c0];
            float4 w1 = *(const float4*)&qw2[i*HID + c0 + 4];
            a0.x += a*w0.x; a0.y += a*w0.y; a0.z += a*w0.z; a0.w += a*w0.w;
            a1.x += a*w1.x; a1.y += a*w1.y; a1.z += a*w1.z; a1.w += a*w1.w;
        }
        l2S[r][c0]   = silu_f(a0.x); l2S[r][c0+1] = silu_f(a0.y);
        l2S[r][c0+2] = silu_f(a0.z); l2S[r][c0+3] = silu_f(a0.w);
        l2S[r][c0+4] = silu_f(a1.x); l2S[r][c0+5] = silu_f(a1.y);
        l2S[r][c0+6] = silu_f(a1.z); l2S[r][c0+7] = silu_f(a1.w);
    }
    __syncthreads();
    {
        float4 a0 = *(const float4*)&qb3[c0];
        float4 a1 = *(const float4*)&qb3[c0 + 4];
        #pragma unroll 4
        for (int i = 0; i < HID; i++) {
            float a = l2S[r][i];
            float4 w0 = *(const float4*)&qw3[i*HID + c0];
            float4 w1 = *(const float4*)&qw3[i*HID + c0 + 4];
            a0.x += a*w0.x; a0.y += a*w0.y; a0.z += a*w0.z; a0.w += a*w0.w;
            a1.x += a*w1.x; a1.y += a*w1.y; a1.z += a*w1.z; a1.w += a*w1.w;
        }
        *(float4*)&qmat[(r0 + r)*LAT + c0] = a0;
        *(float4*)&qmat[(r0 + r)*LAT + c0 + 4] = a1;
    }
}

// ---------------- tensor product per edge -> virr (unchanged from R5) ----------------
__global__ __launch_bounds__(128) void k_tp(
    const float* __restrict__ h_full, const __half* __restrict__ tpwE,
    const int* __restrict__ att_dst,
    const float* __restrict__ envE, const float* __restrict__ y1E,
    float* __restrict__ virr)
{
    int e = blockIdx.x; int t = threadIdx.x;
    int f = att_dst[e];
    __shared__ float x0[M0I];
    __shared__ float x1f[M1I*3];
    __shared__ float xy[M1I];
    __shared__ float y1s[3];
    const float* hf = h_full + f*NODE_DIM;
    if (t < M0I) x0[t] = hf[t];
    if (t < M1I*3) x1f[t] = hf[M0I + t];
    if (t < 3) y1s[t] = y1E[3*e + t];
    __syncthreads();
    if (t < M1I) xy[t] = x1f[3*t]*y1s[0] + x1f[3*t+1]*y1s[1] + x1f[3*t+2]*y1s[2];
    __syncthreads();
    float scale = envE[e];
    const __half* w = tpwE + (long)e*WNUM;
    const float alpha = 0.10206207261596575f;  // 1/sqrt(96)
    const float cc = 0.5773502691896258f;      // 1/sqrt(3)
    if (t < M0O) {
        float t00 = 0.f, t11 = 0.f;
        #pragma unroll 4
        for (int i = 0; i < M0I; i++) t00 += x0[i]*__half2float(w[i*M0O + t]);
        #pragma unroll 4
        for (int i = 0; i < M1I; i++) t11 += xy[i]*__half2float(w[SEG3 + i*M0O + t]);
        virr[f*OUT_DIM + t] = alpha*(t00 + cc*t11)*scale;
    } else if (t < M0O + 3*M1O) {
        int idx = t - M0O; int o = idx/3, m = idx - 3*o;
        float t01 = 0.f, t10 = 0.f;
        #pragma unroll 4
        for (int i = 0; i < M0I; i++) t01 += x0[i]*__half2float(w[SEG1 + i*M1O + o]);
        #pragma unroll 4
        for (int i = 0; i < M1I; i++) t10 += x1f[i*3 + m]*__half2float(w[SEG2 + i*M1O + o]);
        virr[f*OUT_DIM + t] = alpha*cc*(t01*y1s[m] + t10)*scale;
    }
}

// ---------------- attention v3: (b, 8e) blocks, wave-parallel softmax, float4 staging ----------------
__global__ __launch_bounds__(256) void k_att(
    const float* __restrict__ qmat, const float* __restrict__ kmat, const int* __restrict__ inv,
    const float* __restrict__ virr, const float* __restrict__ gexp,
    float* __restrict__ invm)
{
    int b  = blockIdx.x >> 5;
    int e0 = (blockIdx.x & 31) * 8;
    int t = threadIdx.x;
    __shared__ float qS[8][132];
    __shared__ float vS[NN][84];
    __shared__ float aS[8][100];
    __shared__ float gS[8][84];
    __shared__ float ocS[8][84];
    __shared__ float mS[NN];

    {   // qS: 8x128 = 256 float4, one per thread
        int el = t >> 5, i4 = t & 31;
        *(float4*)&qS[el][i4*4] = *(const float4*)&qmat[(b*NE + e0 + el)*LAT + i4*4];
    }
    // vS: 96x80 = 1920 float4 (virr pre-zeroed for unattended rows — no guard)
    for (int u = t; u < NN*20; u += 256) {
        int n = u / 20, c4 = u - 20*(u/20);
        *(float4*)&vS[n][c4*4] = *(const float4*)&virr[(b*NN + n)*OUT_DIM + c4*4];
    }
    if (t < 160) {  // gS: 8x20 float4
        int el = t / 20, c4 = t - 20*(t/20);
        *(float4*)&gS[el][c4*4] = *(const float4*)&gexp[(e0 + el)*OUT_DIM + c4*4];
    }
    if (t < NN) mS[t] = ((unsigned)inv[b*NN + t] < E_ATT) ? 1.0f : 0.0f;
    __syncthreads();

    {   // scores + wave-parallel softmax: half-wave (32 lanes) owns one e-row, 3 n per lane
        int el = t >> 5;
        int ng = t & 31;
        float a0 = 0.f, a1 = 0.f, a2 = 0.f;
        const float* k0p = kmat + (b*NN + ng)*LAT;
        const float* k1p = k0p + 32*LAT;
        const float* k2p = k0p + 64*LAT;
        #pragma unroll 4
        for (int i = 0; i < LAT; i += 4) {
            float4 qv = *(float4*)&qS[el][i];
            float4 k0 = *(const float4*)&k0p[i];
            float4 k1 = *(const float4*)&k1p[i];
            float4 k2 = *(const float4*)&k2p[i];
            a0 += qv.x*k0.x + qv.y*k0.y + qv.z*k0.z + qv.w*k0.w;
            a1 += qv.x*k1.x + qv.y*k1.y + qv.z*k1.z + qv.w*k1.w;
            a2 += qv.x*k2.x + qv.y*k2.y + qv.z*k2.z + qv.w*k2.w;
        }
        const float scale = 0.04419417382415922f;  // (1/HEADS)*HD^-0.5
        float m0 = mS[ng], m1 = mS[ng + 32], m2 = mS[ng + 64];
        float s0 = (m0 != 0.f) ? a0*scale : -1e9f;
        float s1 = (m1 != 0.f) ? a1*scale : -1e9f;
        float s2 = (m2 != 0.f) ? a2*scale : -1e9f;
        // row max across the 32-lane half-wave (xor masks <32 keep halves independent)
        float mx = fmaxf(s0, fmaxf(s1, s2));
        #pragma unroll
        for (int off = 1; off < 32; off <<= 1) mx = fmaxf(mx, __shfl_xor(mx, off));
        float e0v = expf(s0 - mx), e1v = expf(s1 - mx), e2v = expf(s2 - mx);
        float sm = e0v + e1v + e2v;
        #pragma unroll
        for (int off = 1; off < 32; off <<= 1) sm += __shfl_xor(sm, off);
        float r = 1.0f / sm;                 // sm >= 1 (max lane contributes 1)
        float p0 = m0*e0v*r, p1 = m1*e1v*r, p2 = m2*e2v*r;
        float ss = p0 + p1 + p2;
        #pragma unroll
        for (int off = 1; off < 32; off <<= 1) ss += __shfl_xor(ss, off);
        float is = 1.0f / fmaxf(ss, 1e-8f);
        aS[el][ng]      = p0*is;
        aS[el][ng + 32] = p1*is;
        aS[el][ng + 64] = p2*is;
    }
    __syncthreads();

    // out_irrep (8e x 80c as float4) * gate
    if (t < 160) {
        int el = t / 20, c4 = t - 20*(t/20);
        float4 acc = make_float4(0,0,0,0);
        #pragma unroll 4
        for (int n = 0; n < NN; n++) {
            float a = aS[el][n];
            float4 v = *(float4*)&vS[n][c4*4];
            acc.x += a*v.x; acc.y += a*v.y; acc.z += a*v.z; acc.w += a*v.w;
        }
        float4 g = *(float4*)&gS[el][c4*4];
        float4 o; o.x = acc.x*g.x; o.y = acc.y*g.y; o.z = acc.z*g.z; o.w = acc.w*g.w;
        *(float4*)&ocS[el][c4*4] = o;
    }
    __syncthreads();

    // inv features (8e x 48) -> global
    for (int u = t; u < 8*INVD; u += 256) {
        int el = u / INVD, j = u - INVD*(u/INVD);
        float val;
        if (j < M0O) val = ocS[el][j];
        else {
            int o = j - M0O;
            float x = ocS[el][M0O + 3*o], y = ocS[el][M0O + 3*o + 1], zz = ocS[el][M0O + 3*o + 2];
            val = sqrtf(x*x + y*y + zz*zz + 1e-12f);
        }
        invm[(b*NE + e0 + el)*INVD + j] = val;
    }
}

// ---------------- final MLP (unchanged from R5) ----------------
__global__ __launch_bounds__(256) void k_final(
    const float* __restrict__ invm,
    const float* __restrict__ ow1, const float* __restrict__ ob1,
    const float* __restrict__ ow2, const float* __restrict__ ob2,
    const float* __restrict__ ow3, const float* __restrict__ ob3,
    float* __restrict__ out)
{
    int r0 = blockIdx.x * 8;
    int t = threadIdx.x;
    int r = t >> 5, c0 = (t & 31)*4;
    __shared__ float inS[8][INVD];
    __shared__ float l1S[8][HID];
    __shared__ float l2S[8][HID];
    for (int idx = t; idx < 8*INVD; idx += 256) {
        int rr = idx / INVD, j = idx - rr*INVD;
        inS[rr][j] = invm[(r0 + rr)*INVD + j];
    }
    __syncthreads();
    {
        float4 a0 = *(const float4*)&ob1[c0];
        float4 a1 = make_float4(0,0,0,0);
        #pragma unroll 8
        for (int i = 0; i < INVD; i += 2) {
            float x0v = inS[r][i], x1v = inS[r][i+1];
            float4 w0 = *(const float4*)&ow1[i*HID + c0];
            float4 w1 = *(const float4*)&ow1[(i+1)*HID + c0];
            a0.x += x0v*w0.x; a0.y += x0v*w0.y; a0.z += x0v*w0.z; a0.w += x0v*w0.w;
            a1.x += x1v*w1.x; a1.y += x1v*w1.y; a1.z += x1v*w1.z; a1.w += x1v*w1.w;
        }
        l1S[r][c0]   = silu_f(a0.x + a1.x); l1S[r][c0+1] = silu_f(a0.y + a1.y);
        l1S[r][c0+2] = silu_f(a0.z + a1.z); l1S[r][c0+3] = silu_f(a0.w + a1.w);
    }
    __syncthreads();
    {
        float4 a0 = *(const float4*)&ob2[c0];
        float4 a1 = make_float4(0,0,0,0);
        #pragma unroll 8
        for (int i = 0; i < HID; i += 2) {
            float x0v = l1S[r][i], x1v = l1S[r][i+1];
            float4 w0 = *(const float4*)&ow2[i*HID + c0];
            float4 w1 = *(const float4*)&ow2[(i+1)*HID + c0];
            a0.x += x0v*w0.x; a0.y += x0v*w0.y; a0.z += x0v*w0.z; a0.w += x0v*w0.w;
            a1.x += x1v*w1.x; a1.y += x1v*w1.y; a1.z += x1v*w1.z; a1.w += x1v*w1.w;
        }
        l2S[r][c0]   = silu_f(a0.x + a1.x); l2S[r][c0+1] = silu_f(a0.y + a1.y);
        l2S[r][c0+2] = silu_f(a0.z + a1.z); l2S[r][c0+3] = silu_f(a0.w + a1.w);
    }
    __syncthreads();
    {
        float4 a0 = *(const float4*)&ob3[c0];
        float4 a1 = make_float4(0,0,0,0);
        #pragma unroll 8
        for (int i = 0; i < HID; i += 2) {
            float x0v = l2S[r][i], x1v = l2S[r][i+1];
            float4 w0 = *(const float4*)&ow3[i*HID + c0];
            float4 w1 = *(const float4*)&ow3[(i+1)*HID + c0];
            a0.x += x0v*w0.x; a0.y += x0v*w0.y; a0.z += x0v*w0.z; a0.w += x0v*w0.w;
            a1.x += x1v*w1.x; a1.y += x1v*w1.y; a1.z += x1v*w1.z; a1.w += x1v*w1.w;
        }
        float4 o;
        o.x = a0.x + a1.x; o.y = a0.y + a1.y; o.z = a0.z + a1.z; o.w = a0.w + a1.w;
        *(float4*)&out[(r0 + r)*LAT + c0] = o;
    }
}

extern "C" void kernel_launch(void* const* d_in, const int* in_sizes, int n_in,
                              void* d_out, int out_size, void* d_ws, size_t ws_size,
                              hipStream_t stream) {
    const float* h        = (const float*)d_in[0];
    const float* h_full   = (const float*)d_in[1];
    const float* e_feat   = (const float*)d_in[2];
    const float* att_dist = (const float*)d_in[3];
    const float* att_vec  = (const float*)d_in[4];
    const float* z_emb    = (const float*)d_in[5];
    const float* rw1 = (const float*)d_in[6];  const float* rb1 = (const float*)d_in[7];
    const float* rw2 = (const float*)d_in[8];  const float* rb2 = (const float*)d_in[9];
    const float* ew1 = (const float*)d_in[10]; const float* eb1 = (const float*)d_in[11];
    const float* ew2 = (const float*)d_in[12]; const float* eb2 = (const float*)d_in[13];
    const float* qw1 = (const float*)d_in[14]; const float* qb1 = (const float*)d_in[15];
    const float* qw2 = (const float*)d_in[16]; const float* qb2 = (const float*)d_in[17];
    const float* qw3 = (const float*)d_in[18]; const float* qb3 = (const float*)d_in[19];
    const float* kw1 = (const float*)d_in[20]; const float* kb1 = (const float*)d_in[21];
    const float* kw2 = (const float*)d_in[22]; const float* kb2 = (const float*)d_in[23];
    const float* kw3 = (const float*)d_in[24]; const float* kb3 = (const float*)d_in[25];
    const float* ow1 = (const float*)d_in[26]; const float* ob1 = (const float*)d_in[27];
    const float* ow2 = (const float*)d_in[28]; const float* ob2 = (const float*)d_in[29];
    const float* ow3 = (const float*)d_in[30]; const float* ob3 = (const float*)d_in[31];
    const int* z        = (const int*)d_in[32];
    const int* absorber = (const int*)d_in[34];
    const int* att_dst  = (const int*)d_in[35];

    float* ws = (float*)d_ws;
    int*   inv     = (int*)ws;                    // 1536
    float* y1E     = ws + 1536;                   // 3072
    float* envE    = ws + 4608;                   // 1024
    float* hiddenE = ws + 5632;                   // 131072 (1024x128)
    float* kmat    = ws + 136704;                 // 196608 (1536x128)
    float* qmat    = ws + 333312;                 // 524288 (4096x128)
    float* gexp    = ws + 857600;                 // 20480
    float* virr    = ws + 878080;                 // 122880 (1536x80)
    float* habs1   = ws + 1000960;                // 2048
    float* ec      = ws + 1003008;                // 32768
    float* invm    = ws + 1035776;                // 196608 (4096x48)
    __half* tpwE   = (__half*)(ws + 1232384);     // 1024*4608 halves (9.4 MB)

    float* out = (float*)d_out;

    k_prep<<<121, 256, 0, stream>>>(att_dst, att_dist, att_vec, inv, y1E, envE, virr);
    k_stage1<<<STAGE1_BLKS, 256, 0, stream>>>(h, z_emb, z, absorber, e_feat, inv, att_dist,
                                              rw1, rb1, kw1, kb1, kw2, kb2, kw3, kb3,
                                              qw1, ew1, eb1, ew2, eb2,
                                              hiddenE, kmat, ec, habs1, gexp);
    k_tpw<<<dim3(WNUM/128, E_ATT/64), 256, 0, stream>>>(hiddenE, rw2, rb2, tpwE);
    k_q23<<<BB*NE/16, 256, 0, stream>>>(habs1, ec, qb1, qw2, qb2, qw3, qb3, qmat);
    k_tp<<<E_ATT, 128, 0, stream>>>(h_full, tpwE, att_dst, envE, y1E, virr);
    k_att<<<BB*32, 256, 0, stream>>>(qmat, kmat, inv, virr, gexp, invm);
    k_final<<<BB*NE/8, 256, 0, stream>>>(invm, ow1, ob1, ow2, ob2, ow3, ob3, out);
}